// Round 1
// 1353.628 us; speedup vs baseline: 1.2488x; 1.2488x over previous
//
#include <hip/hip_runtime.h>
#include <hip/hip_bf16.h>
#include <cstdio>
#include <cstdint>

#define BS_   128
#define T_    128
#define A_    8
#define D_    128
#define H_    512
#define ROWS_ 1024           // BS*A
#define MTOT_ 131072         // BS*T*A
#define SLAB_ (ROWS_ * H_)   // one timestep slab (X or h), elements

typedef __hip_bfloat16 bf16;
typedef __attribute__((ext_vector_type(4))) float f32x4;
typedef __attribute__((ext_vector_type(8))) short s16x8;
typedef __attribute__((ext_vector_type(4))) short s16x4;

__device__ __forceinline__ void async_ld16(const void* g, const void* lds) {
  __builtin_amdgcn_global_load_lds((const __attribute__((address_space(1))) void*)g,
                                   (__attribute__((address_space(3))) void*)lds,
                                   16, 0, 0);
}
__device__ __forceinline__ s16x8 ldg8(const short* p) { return *(const s16x8*)p; }
__device__ __forceinline__ float sigm(float x) { return 1.f / (1.f + __expf(-x)); }
__device__ __forceinline__ float tanh_f(float x) {
  const float e = __expf(2.f * x);            // inf-safe
  return 1.f - 2.f / (e + 1.f);
}
__device__ __forceinline__ s16x8 cvt8(const float* p) {
  const float4 a = ((const float4*)p)[0];
  const float4 b = ((const float4*)p)[1];
  s16x8 r_;
  r_[0] = __builtin_bit_cast(short, __float2bfloat16(a.x));
  r_[1] = __builtin_bit_cast(short, __float2bfloat16(a.y));
  r_[2] = __builtin_bit_cast(short, __float2bfloat16(a.z));
  r_[3] = __builtin_bit_cast(short, __float2bfloat16(a.w));
  r_[4] = __builtin_bit_cast(short, __float2bfloat16(b.x));
  r_[5] = __builtin_bit_cast(short, __float2bfloat16(b.y));
  r_[6] = __builtin_bit_cast(short, __float2bfloat16(b.z));
  r_[7] = __builtin_bit_cast(short, __float2bfloat16(b.w));
  return r_;
}

// obs [b][t][a][d] fp32 -> obsB [t][b*8+a][d] bf16
__global__ __launch_bounds__(256)
void cvt_obs_kernel(const float* __restrict__ src, bf16* __restrict__ dst) {
  const int o = (blockIdx.x * 256 + threadIdx.x) << 2;
  const int d = o & 127, a = (o >> 7) & 7, t = (o >> 10) & 127, b = o >> 17;
  const float4 v = *(const float4*)(src + o);
  s16x4 pk;
  pk[0] = __builtin_bit_cast(short, __float2bfloat16(v.x));
  pk[1] = __builtin_bit_cast(short, __float2bfloat16(v.y));
  pk[2] = __builtin_bit_cast(short, __float2bfloat16(v.z));
  pk[3] = __builtin_bit_cast(short, __float2bfloat16(v.w));
  *(s16x4*)((short*)dst + ((((size_t)t << 10) + (b << 3) + a) << 7) + d) = pk;
}

__global__ __launch_bounds__(256)
void cvt_kernel(const float* __restrict__ src, bf16* __restrict__ dst) {
  const int i = (blockIdx.x * 256 + threadIdx.x) << 2;
  const float4 v = *(const float4*)(src + i);
  s16x4 o;
  o[0] = __builtin_bit_cast(short, __float2bfloat16(v.x));
  o[1] = __builtin_bit_cast(short, __float2bfloat16(v.y));
  o[2] = __builtin_bit_cast(short, __float2bfloat16(v.z));
  o[3] = __builtin_bit_cast(short, __float2bfloat16(v.w));
  *(s16x4*)((short*)dst + i) = o;
}

// 32 wave-slot counters (rt,w), each padded to its own 128B line: 1024 dwords
__global__ __launch_bounds__(256)
void bar_init_kernel(unsigned* __restrict__ bar) {
  const int i = threadIdx.x;
#pragma unroll
  for (int k = 0; k < 4; ++k) bar[(k << 8) + i] = 0u;
}

// ---------------------------------------------------------------------------
// X = relu(obsB @ W1^T + b1)
// ---------------------------------------------------------------------------
__global__ __launch_bounds__(256)
void xgemm_kernel(const bf16* __restrict__ Ag, const bf16* __restrict__ Wg,
                  const float* __restrict__ bias, bf16* __restrict__ Og) {
  const int bid = blockIdx.x;
  const int m0 = (bid >> 2) << 7;
  const int n0 = (bid & 3) << 7;
  const int tid = threadIdx.x;
  const int w = tid >> 6, lane = tid & 63;
  const int r = lane & 15, q = lane >> 4;
  const int wm = w & 1, wn = w >> 1;

  __shared__ short As[128 * 32];
  __shared__ short Bs[128 * 32];

  f32x4 acc[4][4];
  const f32x4 vz = {0.f, 0.f, 0.f, 0.f};
#pragma unroll
  for (int i = 0; i < 4; ++i)
#pragma unroll
    for (int j = 0; j < 4; ++j) acc[i][j] = vz;

  const int lrow = lane >> 2;
  const int kcol = (lane & 3) << 3;

  for (int kt = 0; kt < 4; ++kt) {          // K = 128
    __syncthreads();
    const int kbase = kt << 5;
#pragma unroll
    for (int jj = 0; jj < 2; ++jj) {
      const int c = (w << 1) + jj;
      const int m = (c << 4) + lrow;
      async_ld16(Ag + (size_t)(m0 + m) * D_ + kbase + kcol, &As[c << 9]);
      async_ld16(Wg + (size_t)(n0 + m) * D_ + kbase + kcol, &Bs[c << 9]);
    }
    __syncthreads();

    s16x8 af[4], bfr[4];
#pragma unroll
    for (int x = 0; x < 4; ++x) {
      af[x]  = *(const s16x8*)&As[((wm << 6) + (x << 4) + r) * 32 + (q << 3)];
      bfr[x] = *(const s16x8*)&Bs[((wn << 6) + (x << 4) + r) * 32 + (q << 3)];
    }
#pragma unroll
    for (int i = 0; i < 4; ++i)
#pragma unroll
      for (int j = 0; j < 4; ++j)
        acc[i][j] = __builtin_amdgcn_mfma_f32_16x16x32_bf16(af[i], bfr[j],
                                                            acc[i][j], 0, 0, 0);
  }

#pragma unroll
  for (int j = 0; j < 4; ++j) {
    const int gn = n0 + (wn << 6) + (j << 4) + r;
    const float bb = bias[gn];
#pragma unroll
    for (int i = 0; i < 4; ++i) {
      const int gmb = m0 + (wm << 6) + (i << 4) + (q << 2);
#pragma unroll
      for (int ii = 0; ii < 4; ++ii) {
        const int gm = gmb + ii;
        Og[(size_t)gm * H_ + gn] =
            __float2bfloat16(fmaxf(acc[i][j][ii] + bb, 0.f));
      }
    }
  }
}

// ---------------------------------------------------------------------------
// Persistent GRU scan, round-9: PER-WAVE-SLOT pipelines + full-depth loads.
//  * Key observation: wave w's 32 rows (rw = rt*128 + w*32) are produced
//    ONLY by wave w of the 32 sibling (rt,*) blocks. Sync granularity drops
//    from block to wave-slot: 32 counters (rt,w); producer wave does
//    s_waitcnt vmcnt(0) + one fetch_add; consumer wave polls ONLY its slot
//    counter. ZERO __syncthreads in the steady loop -> no 4-wave convoys,
//    4x less same-line atomic contention, 1024 independent pipelines.
//  * Whh moved AGPR -> LDS (48 KB; Wih 48 KB + Whh 48 KB = exactly the
//    96 KB dyn-LDS request). Frees ~190 regs, spent on:
//  * FULL-DEPTH load issue: all 32 h-loads and all 32 X-loads in flight
//    (ring-8/ring-4 covered only 930/350 cyc vs ~900-1800 cyc first-touch
//    L3/HBM latency -> gi phase alone was ~2.5-4 us of exposed latency;
//    FETCH_SIZE 155 MB ~= X's 134 MB proves X streams from HBM).
//  * h: t-indexed virgin slabs, L3-direct packed agent stores (unchanged).
// ---------------------------------------------------------------------------
__global__ __launch_bounds__(256, 1)
void scan_kernel(const float* __restrict__ Wih32, const float* __restrict__ Whh32,
                 const float* __restrict__ bih, const float* __restrict__ bhh,
                 const float* __restrict__ Wv, const short* __restrict__ Xs,
                 bf16* __restrict__ Hseq, float* __restrict__ Vp127,
                 unsigned* __restrict__ bar) {
  extern __shared__ short sm[];   // [0,24576): Wih  [24576,49152): Whh (lane-packed)

  const int bid = blockIdx.x;
  const int rt = bid & 7, jt = bid >> 3;
  const int j0 = jt << 4;
  const int tid = threadIdx.x;
  const int w = tid >> 6, lane = tid & 63;
  const int r = lane & 15, q = lane >> 4;
  const int rw = (rt << 7) + (w << 5);   // wave's 32 rows
  unsigned* __restrict__ barw = &bar[((rt << 2) + w) << 5];  // slot counter

  // ---- Wih + Whh slices fp32 -> bf16, lane-packed into LDS (once) ----
#pragma unroll
  for (int i = 0; i < 12; ++i) {
    const int c = (i << 2) + w;          // chunk 0..47 = (g, kt)
    const int g = c >> 4, kt = c & 15;
    const size_t woff = (size_t)((g << 9) + j0 + r) * H_ + (kt << 5) + (q << 3);
    *(s16x8*)&sm[(c << 9) + (lane << 3)]          = cvt8(Wih32 + woff);
    *(s16x8*)&sm[24576 + (c << 9) + (lane << 3)]  = cvt8(Whh32 + woff);
  }

  const int j = j0 + r;
  const float bR  = bih[j] + bhh[j];
  const float bZ  = bih[512 + j] + bhh[512 + j];
  const float bIN = bih[1024 + j];
  const float bHN = bhh[1024 + j];
  const float wvj = Wv[j];

  float hm[2][4] = {{0.f, 0.f, 0.f, 0.f}, {0.f, 0.f, 0.f, 0.f}};
  const f32x4 vz = {0.f, 0.f, 0.f, 0.f};

  const size_t aoff0 = (size_t)(rw + r) * H_ + (q << 3);
  const size_t aoff1 = aoff0 + (size_t)16 * H_;
  short* Hs = (short*)Hseq;

  __syncthreads();   // LDS staged (only barrier in the kernel)

  // ---- prologue: gi(0) from X slab 0, full-depth issue ----
  f32x4 gia[3][2];
  {
    const short* xb = Xs;
    s16x8 ax0[16], ax1[16];
#pragma unroll
    for (int p = 0; p < 16; ++p) {
      ax0[p] = ldg8(xb + aoff0 + (p << 5));
      ax1[p] = ldg8(xb + aoff1 + (p << 5));
    }
#pragma unroll
    for (int g = 0; g < 3; ++g) { gia[g][0] = vz; gia[g][1] = vz; }
#pragma unroll
    for (int kt = 0; kt < 16; ++kt)
#pragma unroll
      for (int g = 0; g < 3; ++g) {
        const s16x8 b = *(const s16x8*)&sm[(((g << 4) + kt) << 9) + (lane << 3)];
        gia[g][0] = __builtin_amdgcn_mfma_f32_16x16x32_bf16(ax0[kt], b, gia[g][0], 0, 0, 0);
        gia[g][1] = __builtin_amdgcn_mfma_f32_16x16x32_bf16(ax1[kt], b, gia[g][1], 0, 0, 0);
      }
  }

  for (int t = 0; t < T_; ++t) {
    // ---- per-wave-slot wait (rows rw..rw+31 of slab t-1 complete) ----
    f32x4 gha[3][2];
#pragma unroll
    for (int g = 0; g < 3; ++g) { gha[g][0] = vz; gha[g][1] = vz; }
    if (t > 0) {
      const unsigned tgt = (unsigned)t << 5;              // 32*t arrivals
      unsigned spins = 0;
      while (__hip_atomic_load(barw, __ATOMIC_RELAXED,
                               __HIP_MEMORY_SCOPE_AGENT) < tgt) {
        __builtin_amdgcn_s_sleep(1);
        if (++spins > 8000000u) break;                    // dead-man valve
      }

      // ---- gh: all 32 h-loads in flight + LDS Whh B-frags ----
      const short* hb = Hs + (size_t)(t - 1) * SLAB_;
      s16x8 ah0[16], ah1[16];
#pragma unroll
      for (int p = 0; p < 16; ++p) {
        ah0[p] = ldg8(hb + aoff0 + (p << 5));
        ah1[p] = ldg8(hb + aoff1 + (p << 5));
      }
#pragma unroll
      for (int kt = 0; kt < 16; ++kt)
#pragma unroll
        for (int g = 0; g < 3; ++g) {
          const s16x8 b = *(const s16x8*)&sm[24576 + (((g << 4) + kt) << 9) + (lane << 3)];
          gha[g][0] = __builtin_amdgcn_mfma_f32_16x16x32_bf16(ah0[kt], b, gha[g][0], 0, 0, 0);
          gha[g][1] = __builtin_amdgcn_mfma_f32_16x16x32_bf16(ah1[kt], b, gha[g][1], 0, 0, 0);
        }
    }

    // ---- gates, h update; t=127: value partials from registers ----
    short* hrow = Hs + (size_t)t * SLAB_;
    const bool last = (t == T_ - 1);
#pragma unroll
    for (int i = 0; i < 2; ++i)
#pragma unroll
      for (int ii = 0; ii < 4; ++ii) {
        const int row = rw + (i << 4) + (q << 2) + ii;
        const float rr = sigm(gia[0][i][ii] + gha[0][i][ii] + bR);
        const float zz = sigm(gia[1][i][ii] + gha[1][i][ii] + bZ);
        const float nn = tanh_f(gia[2][i][ii] + bIN + rr * (gha[2][i][ii] + bHN));
        const float hnew = (1.f - zz) * nn + zz * hm[i][ii];
        hm[i][ii] = hnew;
        if (!last) {
          // packed lane-pair L3-direct h store (cols j, j^1)
          const unsigned hv =
              (unsigned)(unsigned short)__builtin_bit_cast(unsigned short,
                                                           __float2bfloat16(hnew));
          const unsigned pv = (unsigned)__shfl_xor((int)hv, 1);
          if (!(r & 1)) {
            const unsigned pk = hv | (pv << 16);
            __hip_atomic_store((unsigned*)(hrow + (size_t)row * H_ + j0 + r), pk,
                               __ATOMIC_RELAXED, __HIP_MEMORY_SCOPE_AGENT);
          }
        } else {
          float vpv = wvj * hnew;
          vpv += __shfl_xor(vpv, 1);
          vpv += __shfl_xor(vpv, 2);
          vpv += __shfl_xor(vpv, 4);
          vpv += __shfl_xor(vpv, 8);       // sum 16 j-lanes
          if (r == 0) Vp127[(jt << 10) + row] = vpv;
        }
      }

    if (last) break;

    // ---- per-wave arrive: drain own h stores, bump slot counter ----
    asm volatile("s_waitcnt vmcnt(0)" ::: "memory");
    if (lane == 0)
      __hip_atomic_fetch_add(barw, 1u, __ATOMIC_RELAXED,
                             __HIP_MEMORY_SCOPE_AGENT);

    // ---- gi(t+1) in the arrive-shadow: full-depth X issue ----
    {
      const short* xb = Xs + (size_t)(t + 1) * SLAB_;
      s16x8 ax0[16], ax1[16];
#pragma unroll
      for (int p = 0; p < 16; ++p) {
        ax0[p] = ldg8(xb + aoff0 + (p << 5));
        ax1[p] = ldg8(xb + aoff1 + (p << 5));
      }
#pragma unroll
      for (int g = 0; g < 3; ++g) { gia[g][0] = vz; gia[g][1] = vz; }
#pragma unroll
      for (int kt = 0; kt < 16; ++kt)
#pragma unroll
        for (int g = 0; g < 3; ++g) {
          const s16x8 b = *(const s16x8*)&sm[(((g << 4) + kt) << 9) + (lane << 3)];
          gia[g][0] = __builtin_amdgcn_mfma_f32_16x16x32_bf16(ax0[kt], b, gia[g][0], 0, 0, 0);
          gia[g][1] = __builtin_amdgcn_mfma_f32_16x16x32_bf16(ax1[kt], b, gia[g][1], 0, 0, 0);
        }
    }
  }
}

// ---------------------------------------------------------------------------
// out[b][t][a] = bv + Wv . h_t(row)  (h from Hseq for t<127, Vp127 for t=127)
// block = (t, rowgroup of 8); thread (r8=tid>>5, c=tid&31): cols c*16..+15
// ---------------------------------------------------------------------------
__global__ __launch_bounds__(256)
void out_kernel(const bf16* __restrict__ Hseq, const float* __restrict__ Vp127,
                const float* __restrict__ Wv, const float* __restrict__ bv,
                float* __restrict__ out) {
  __shared__ float wvs[512];
  const int bid = blockIdx.x;           // 0..16383
  const int t = bid >> 7, rg = bid & 127;
  const int tid = threadIdx.x;
  const int r8 = tid >> 5, c = tid & 31;
  const int row = (rg << 3) + r8;
  if (tid < 128) *(float4*)&wvs[tid << 2] = *(const float4*)&Wv[tid << 2];
  __syncthreads();

  float s = 0.f;
  if (t < T_ - 1) {
    const short* hp = (const short*)Hseq + (size_t)t * SLAB_ + ((size_t)row << 9)
                    + (c << 4);
    const s16x8 h0 = ldg8(hp), h1 = ldg8(hp + 8);
    const float* wp = &wvs[c << 4];
#pragma unroll
    for (int k = 0; k < 8; ++k)
      s += wp[k] * __bfloat162float(__builtin_bit_cast(__hip_bfloat16, (unsigned short)h0[k]));
#pragma unroll
    for (int k = 0; k < 8; ++k)
      s += wp[8 + k] * __bfloat162float(__builtin_bit_cast(__hip_bfloat16, (unsigned short)h1[k]));
  } else {
    s = Vp127[(c << 10) + row];          // 32 partials, one per lane
  }
  s += __shfl_xor(s, 1);
  s += __shfl_xor(s, 2);
  s += __shfl_xor(s, 4);
  s += __shfl_xor(s, 8);
  s += __shfl_xor(s, 16);               // sum over 32 c-lanes
  if (c == 0)
    out[((row >> 3) << 10) + (t << 3) + (row & 7)] = s + bv[0];
}

extern "C" void kernel_launch(void* const* d_in, const int* in_sizes, int n_in,
                              void* d_out, int out_size, void* d_ws, size_t ws_size,
                              hipStream_t stream) {
  (void)in_sizes; (void)n_in; (void)out_size;
  const float* obs = (const float*)d_in[0];
  const float* W1  = (const float*)d_in[1];
  const float* b1  = (const float*)d_in[2];
  const float* Wih = (const float*)d_in[3];
  const float* bih = (const float*)d_in[4];
  const float* Whh = (const float*)d_in[5];
  const float* bhh = (const float*)d_in[6];
  const float* Wv  = (const float*)d_in[7];
  const float* bv  = (const float*)d_in[8];
  float* out = (float*)d_out;

  // ws (256 MiB): Hseq 127 slabs | X 128 slabs | spare 1 MiB (Vp127 + bar)
  //   obsB aliases Hseq slabs 0..31, W1B slab 32 (dead before h writes)
  char* ws = (char*)d_ws;
  bf16*  Hseq = (bf16*)ws;                                  // 127 MiB
  bf16*  obsB = Hseq;
  bf16*  W1B  = Hseq + (size_t)32 * SLAB_;
  bf16*  X    = (bf16*)(ws + (size_t)127 * SLAB_ * 2);      // 128 MiB
  char*  spare = ws + (size_t)255 * SLAB_ * 2;              // 1 MiB
  float* Vp127 = (float*)spare;                             // 128 KiB
  unsigned* bar = (unsigned*)(spare + 256 * 1024);          // 32 padded ctrs (4 KiB)
  const size_t need = (size_t)256 * SLAB_ * 2;
  if (ws_size < need) {
    fprintf(stderr, "[kernel_launch] WS TOO SMALL: need %zu have %zu\n",
            need, ws_size);
    fflush(stderr);
  }

  hipFuncSetAttribute((const void*)scan_kernel,
                      hipFuncAttributeMaxDynamicSharedMemorySize, 98304);

  cvt_obs_kernel<<<16384, 256, 0, stream>>>(obs, obsB);
  cvt_kernel<<<64, 256, 0, stream>>>(W1, W1B);
  bar_init_kernel<<<1, 256, 0, stream>>>(bar);
  xgemm_kernel<<<4096, 256, 0, stream>>>(obsB, W1B, b1, X);
  // 96 KB dyn-LDS (Wih 48K + Whh 48K, fully used) pins 1 block/CU
  scan_kernel<<<256, 256, 98304, stream>>>(Wih, Whh, bih, bhh, Wv, (const short*)X,
                                           Hseq, Vp127, bar);
  out_kernel<<<16384, 256, 0, stream>>>(Hseq, Vp127, Wv, bv, out);
}

// Round 2
// 1323.250 us; speedup vs baseline: 1.2774x; 1.0230x over previous
//
#include <hip/hip_runtime.h>
#include <hip/hip_bf16.h>
#include <cstdio>
#include <cstdint>

#define BS_   128
#define T_    128
#define A_    8
#define D_    128
#define H_    512
#define ROWS_ 1024           // BS*A
#define MTOT_ 131072         // BS*T*A
#define SLAB_ (ROWS_ * H_)   // one timestep slab (X or h), elements

typedef __hip_bfloat16 bf16;
typedef __attribute__((ext_vector_type(4))) float f32x4;
typedef __attribute__((ext_vector_type(8))) short s16x8;
typedef __attribute__((ext_vector_type(4))) short s16x4;

__device__ __forceinline__ void async_ld16(const void* g, const void* lds) {
  __builtin_amdgcn_global_load_lds((const __attribute__((address_space(1))) void*)g,
                                   (__attribute__((address_space(3))) void*)lds,
                                   16, 0, 0);
}
__device__ __forceinline__ s16x8 ldg8(const short* p) { return *(const s16x8*)p; }
__device__ __forceinline__ float sigm(float x) { return 1.f / (1.f + __expf(-x)); }
__device__ __forceinline__ float tanh_f(float x) {
  const float e = __expf(2.f * x);            // inf-safe
  return 1.f - 2.f / (e + 1.f);
}
__device__ __forceinline__ s16x8 cvt8(const float* p) {
  const float4 a = ((const float4*)p)[0];
  const float4 b = ((const float4*)p)[1];
  s16x8 r_;
  r_[0] = __builtin_bit_cast(short, __float2bfloat16(a.x));
  r_[1] = __builtin_bit_cast(short, __float2bfloat16(a.y));
  r_[2] = __builtin_bit_cast(short, __float2bfloat16(a.z));
  r_[3] = __builtin_bit_cast(short, __float2bfloat16(a.w));
  r_[4] = __builtin_bit_cast(short, __float2bfloat16(b.x));
  r_[5] = __builtin_bit_cast(short, __float2bfloat16(b.y));
  r_[6] = __builtin_bit_cast(short, __float2bfloat16(b.z));
  r_[7] = __builtin_bit_cast(short, __float2bfloat16(b.w));
  return r_;
}

// obs [b][t][a][d] fp32 -> obsB [t][b*8+a][d] bf16
__global__ __launch_bounds__(256)
void cvt_obs_kernel(const float* __restrict__ src, bf16* __restrict__ dst) {
  const int o = (blockIdx.x * 256 + threadIdx.x) << 2;
  const int d = o & 127, a = (o >> 7) & 7, t = (o >> 10) & 127, b = o >> 17;
  const float4 v = *(const float4*)(src + o);
  s16x4 pk;
  pk[0] = __builtin_bit_cast(short, __float2bfloat16(v.x));
  pk[1] = __builtin_bit_cast(short, __float2bfloat16(v.y));
  pk[2] = __builtin_bit_cast(short, __float2bfloat16(v.z));
  pk[3] = __builtin_bit_cast(short, __float2bfloat16(v.w));
  *(s16x4*)((short*)dst + ((((size_t)t << 10) + (b << 3) + a) << 7) + d) = pk;
}

__global__ __launch_bounds__(256)
void cvt_kernel(const float* __restrict__ src, bf16* __restrict__ dst) {
  const int i = (blockIdx.x * 256 + threadIdx.x) << 2;
  const float4 v = *(const float4*)(src + i);
  s16x4 o;
  o[0] = __builtin_bit_cast(short, __float2bfloat16(v.x));
  o[1] = __builtin_bit_cast(short, __float2bfloat16(v.y));
  o[2] = __builtin_bit_cast(short, __float2bfloat16(v.z));
  o[3] = __builtin_bit_cast(short, __float2bfloat16(v.w));
  *(s16x4*)((short*)dst + i) = o;
}

// 32 wave-slot counters (rt,w), each padded to its own 128B line: 1024 dwords
__global__ __launch_bounds__(256)
void bar_init_kernel(unsigned* __restrict__ bar) {
  const int i = threadIdx.x;
#pragma unroll
  for (int k = 0; k < 4; ++k) bar[(k << 8) + i] = 0u;
}

// ---------------------------------------------------------------------------
// X = relu(obsB @ W1^T + b1)
// ---------------------------------------------------------------------------
__global__ __launch_bounds__(256)
void xgemm_kernel(const bf16* __restrict__ Ag, const bf16* __restrict__ Wg,
                  const float* __restrict__ bias, bf16* __restrict__ Og) {
  const int bid = blockIdx.x;
  const int m0 = (bid >> 2) << 7;
  const int n0 = (bid & 3) << 7;
  const int tid = threadIdx.x;
  const int w = tid >> 6, lane = tid & 63;
  const int r = lane & 15, q = lane >> 4;
  const int wm = w & 1, wn = w >> 1;

  __shared__ short As[128 * 32];
  __shared__ short Bs[128 * 32];

  f32x4 acc[4][4];
  const f32x4 vz = {0.f, 0.f, 0.f, 0.f};
#pragma unroll
  for (int i = 0; i < 4; ++i)
#pragma unroll
    for (int j = 0; j < 4; ++j) acc[i][j] = vz;

  const int lrow = lane >> 2;
  const int kcol = (lane & 3) << 3;

  for (int kt = 0; kt < 4; ++kt) {          // K = 128
    __syncthreads();
    const int kbase = kt << 5;
#pragma unroll
    for (int jj = 0; jj < 2; ++jj) {
      const int c = (w << 1) + jj;
      const int m = (c << 4) + lrow;
      async_ld16(Ag + (size_t)(m0 + m) * D_ + kbase + kcol, &As[c << 9]);
      async_ld16(Wg + (size_t)(n0 + m) * D_ + kbase + kcol, &Bs[c << 9]);
    }
    __syncthreads();

    s16x8 af[4], bfr[4];
#pragma unroll
    for (int x = 0; x < 4; ++x) {
      af[x]  = *(const s16x8*)&As[((wm << 6) + (x << 4) + r) * 32 + (q << 3)];
      bfr[x] = *(const s16x8*)&Bs[((wn << 6) + (x << 4) + r) * 32 + (q << 3)];
    }
#pragma unroll
    for (int i = 0; i < 4; ++i)
#pragma unroll
      for (int j = 0; j < 4; ++j)
        acc[i][j] = __builtin_amdgcn_mfma_f32_16x16x32_bf16(af[i], bfr[j],
                                                            acc[i][j], 0, 0, 0);
  }

#pragma unroll
  for (int j = 0; j < 4; ++j) {
    const int gn = n0 + (wn << 6) + (j << 4) + r;
    const float bb = bias[gn];
#pragma unroll
    for (int i = 0; i < 4; ++i) {
      const int gmb = m0 + (wm << 6) + (i << 4) + (q << 2);
#pragma unroll
      for (int ii = 0; ii < 4; ++ii) {
        const int gm = gmb + ii;
        Og[(size_t)gm * H_ + gn] =
            __float2bfloat16(fmaxf(acc[i][j][ii] + bb, 0.f));
      }
    }
  }
}

// ---------------------------------------------------------------------------
// Persistent GRU scan, round-10: FORCED full-depth loads.
//  * Round-9 post-mortem: VGPR_Count=72 proves the scheduler SANK the
//    "full-depth" ax/ah load clusters back to just-before-use (ax0[16]+
//    ax1[16] alone need 128 VGPRs). Effective flight depth ~2-4 -> each
//    gemm phase was still 8-16 serialized ~600-1800cy latency windows.
//  * Fix: __builtin_amdgcn_sched_barrier(0) between each load cluster and
//    its MFMA cluster. MachineScheduler cannot move instrs across it, so
//    all 32 loads/lane issue first and RA must keep them live. LDS (96KB)
//    pins 1 block/CU -> 1 wave/SIMD -> 512-VGPR budget; expect ~200+ VGPR.
//  * Everything else unchanged from round-9: per-wave-slot counters (zero
//    __syncthreads in steady loop), Wih+Whh both lane-packed in LDS,
//    t-indexed virgin h slabs, L3-direct packed agent stores, per-wave
//    vmcnt(0)+fetch_add arrive, gi(t+1) issued in the arrive-shadow.
// ---------------------------------------------------------------------------
__global__ __launch_bounds__(256, 1)
void scan_kernel(const float* __restrict__ Wih32, const float* __restrict__ Whh32,
                 const float* __restrict__ bih, const float* __restrict__ bhh,
                 const float* __restrict__ Wv, const short* __restrict__ Xs,
                 bf16* __restrict__ Hseq, float* __restrict__ Vp127,
                 unsigned* __restrict__ bar) {
  extern __shared__ short sm[];   // [0,24576): Wih  [24576,49152): Whh (lane-packed)

  const int bid = blockIdx.x;
  const int rt = bid & 7, jt = bid >> 3;
  const int j0 = jt << 4;
  const int tid = threadIdx.x;
  const int w = tid >> 6, lane = tid & 63;
  const int r = lane & 15, q = lane >> 4;
  const int rw = (rt << 7) + (w << 5);   // wave's 32 rows
  unsigned* __restrict__ barw = &bar[((rt << 2) + w) << 5];  // slot counter

  // ---- Wih + Whh slices fp32 -> bf16, lane-packed into LDS (once) ----
#pragma unroll
  for (int i = 0; i < 12; ++i) {
    const int c = (i << 2) + w;          // chunk 0..47 = (g, kt)
    const int g = c >> 4, kt = c & 15;
    const size_t woff = (size_t)((g << 9) + j0 + r) * H_ + (kt << 5) + (q << 3);
    *(s16x8*)&sm[(c << 9) + (lane << 3)]          = cvt8(Wih32 + woff);
    *(s16x8*)&sm[24576 + (c << 9) + (lane << 3)]  = cvt8(Whh32 + woff);
  }

  const int j = j0 + r;
  const float bR  = bih[j] + bhh[j];
  const float bZ  = bih[512 + j] + bhh[512 + j];
  const float bIN = bih[1024 + j];
  const float bHN = bhh[1024 + j];
  const float wvj = Wv[j];

  float hm[2][4] = {{0.f, 0.f, 0.f, 0.f}, {0.f, 0.f, 0.f, 0.f}};
  const f32x4 vz = {0.f, 0.f, 0.f, 0.f};

  const size_t aoff0 = (size_t)(rw + r) * H_ + (q << 3);
  const size_t aoff1 = aoff0 + (size_t)16 * H_;
  short* Hs = (short*)Hseq;

  __syncthreads();   // LDS staged (only barrier in the kernel)

  // ---- prologue: gi(0) from X slab 0, full-depth issue (pinned) ----
  f32x4 gia[3][2];
  {
    const short* xb = Xs;
    s16x8 ax0[16], ax1[16];
#pragma unroll
    for (int p = 0; p < 16; ++p) {
      ax0[p] = ldg8(xb + aoff0 + (p << 5));
      ax1[p] = ldg8(xb + aoff1 + (p << 5));
    }
    __builtin_amdgcn_sched_barrier(0);   // keep all 32 loads issued & live
#pragma unroll
    for (int g = 0; g < 3; ++g) { gia[g][0] = vz; gia[g][1] = vz; }
#pragma unroll
    for (int kt = 0; kt < 16; ++kt)
#pragma unroll
      for (int g = 0; g < 3; ++g) {
        const s16x8 b = *(const s16x8*)&sm[(((g << 4) + kt) << 9) + (lane << 3)];
        gia[g][0] = __builtin_amdgcn_mfma_f32_16x16x32_bf16(ax0[kt], b, gia[g][0], 0, 0, 0);
        gia[g][1] = __builtin_amdgcn_mfma_f32_16x16x32_bf16(ax1[kt], b, gia[g][1], 0, 0, 0);
      }
  }

  for (int t = 0; t < T_; ++t) {
    // ---- per-wave-slot wait (rows rw..rw+31 of slab t-1 complete) ----
    f32x4 gha[3][2];
#pragma unroll
    for (int g = 0; g < 3; ++g) { gha[g][0] = vz; gha[g][1] = vz; }
    if (t > 0) {
      const unsigned tgt = (unsigned)t << 5;              // 32*t arrivals
      unsigned spins = 0;
      while (__hip_atomic_load(barw, __ATOMIC_RELAXED,
                               __HIP_MEMORY_SCOPE_AGENT) < tgt) {
        __builtin_amdgcn_s_sleep(1);
        if (++spins > 8000000u) break;                    // dead-man valve
      }

      // ---- gh: all 32 h-loads in flight (pinned) + LDS Whh B-frags ----
      const short* hb = Hs + (size_t)(t - 1) * SLAB_;
      s16x8 ah0[16], ah1[16];
#pragma unroll
      for (int p = 0; p < 16; ++p) {
        ah0[p] = ldg8(hb + aoff0 + (p << 5));
        ah1[p] = ldg8(hb + aoff1 + (p << 5));
      }
      __builtin_amdgcn_sched_barrier(0); // keep all 32 loads issued & live
#pragma unroll
      for (int kt = 0; kt < 16; ++kt)
#pragma unroll
        for (int g = 0; g < 3; ++g) {
          const s16x8 b = *(const s16x8*)&sm[24576 + (((g << 4) + kt) << 9) + (lane << 3)];
          gha[g][0] = __builtin_amdgcn_mfma_f32_16x16x32_bf16(ah0[kt], b, gha[g][0], 0, 0, 0);
          gha[g][1] = __builtin_amdgcn_mfma_f32_16x16x32_bf16(ah1[kt], b, gha[g][1], 0, 0, 0);
        }
    }

    // ---- gates, h update; t=127: value partials from registers ----
    short* hrow = Hs + (size_t)t * SLAB_;
    const bool last = (t == T_ - 1);
#pragma unroll
    for (int i = 0; i < 2; ++i)
#pragma unroll
      for (int ii = 0; ii < 4; ++ii) {
        const int row = rw + (i << 4) + (q << 2) + ii;
        const float rr = sigm(gia[0][i][ii] + gha[0][i][ii] + bR);
        const float zz = sigm(gia[1][i][ii] + gha[1][i][ii] + bZ);
        const float nn = tanh_f(gia[2][i][ii] + bIN + rr * (gha[2][i][ii] + bHN));
        const float hnew = (1.f - zz) * nn + zz * hm[i][ii];
        hm[i][ii] = hnew;
        if (!last) {
          // packed lane-pair L3-direct h store (cols j, j^1)
          const unsigned hv =
              (unsigned)(unsigned short)__builtin_bit_cast(unsigned short,
                                                           __float2bfloat16(hnew));
          const unsigned pv = (unsigned)__shfl_xor((int)hv, 1);
          if (!(r & 1)) {
            const unsigned pk = hv | (pv << 16);
            __hip_atomic_store((unsigned*)(hrow + (size_t)row * H_ + j0 + r), pk,
                               __ATOMIC_RELAXED, __HIP_MEMORY_SCOPE_AGENT);
          }
        } else {
          float vpv = wvj * hnew;
          vpv += __shfl_xor(vpv, 1);
          vpv += __shfl_xor(vpv, 2);
          vpv += __shfl_xor(vpv, 4);
          vpv += __shfl_xor(vpv, 8);       // sum 16 j-lanes
          if (r == 0) Vp127[(jt << 10) + row] = vpv;
        }
      }

    if (last) break;

    // ---- per-wave arrive: drain own h stores, bump slot counter ----
    asm volatile("s_waitcnt vmcnt(0)" ::: "memory");
    if (lane == 0)
      __hip_atomic_fetch_add(barw, 1u, __ATOMIC_RELAXED,
                             __HIP_MEMORY_SCOPE_AGENT);

    // ---- gi(t+1) in the arrive-shadow: full-depth X issue (pinned) ----
    {
      const short* xb = Xs + (size_t)(t + 1) * SLAB_;
      s16x8 ax0[16], ax1[16];
#pragma unroll
      for (int p = 0; p < 16; ++p) {
        ax0[p] = ldg8(xb + aoff0 + (p << 5));
        ax1[p] = ldg8(xb + aoff1 + (p << 5));
      }
      __builtin_amdgcn_sched_barrier(0); // keep all 32 loads issued & live
#pragma unroll
      for (int g = 0; g < 3; ++g) { gia[g][0] = vz; gia[g][1] = vz; }
#pragma unroll
      for (int kt = 0; kt < 16; ++kt)
#pragma unroll
        for (int g = 0; g < 3; ++g) {
          const s16x8 b = *(const s16x8*)&sm[(((g << 4) + kt) << 9) + (lane << 3)];
          gia[g][0] = __builtin_amdgcn_mfma_f32_16x16x32_bf16(ax0[kt], b, gia[g][0], 0, 0, 0);
          gia[g][1] = __builtin_amdgcn_mfma_f32_16x16x32_bf16(ax1[kt], b, gia[g][1], 0, 0, 0);
        }
    }
  }
}

// ---------------------------------------------------------------------------
// out[b][t][a] = bv + Wv . h_t(row)  (h from Hseq for t<127, Vp127 for t=127)
// block = (t, rowgroup of 8); thread (r8=tid>>5, c=tid&31): cols c*16..+15
// ---------------------------------------------------------------------------
__global__ __launch_bounds__(256)
void out_kernel(const bf16* __restrict__ Hseq, const float* __restrict__ Vp127,
                const float* __restrict__ Wv, const float* __restrict__ bv,
                float* __restrict__ out) {
  __shared__ float wvs[512];
  const int bid = blockIdx.x;           // 0..16383
  const int t = bid >> 7, rg = bid & 127;
  const int tid = threadIdx.x;
  const int r8 = tid >> 5, c = tid & 31;
  const int row = (rg << 3) + r8;
  if (tid < 128) *(float4*)&wvs[tid << 2] = *(const float4*)&Wv[tid << 2];
  __syncthreads();

  float s = 0.f;
  if (t < T_ - 1) {
    const short* hp = (const short*)Hseq + (size_t)t * SLAB_ + ((size_t)row << 9)
                    + (c << 4);
    const s16x8 h0 = ldg8(hp), h1 = ldg8(hp + 8);
    const float* wp = &wvs[c << 4];
#pragma unroll
    for (int k = 0; k < 8; ++k)
      s += wp[k] * __bfloat162float(__builtin_bit_cast(__hip_bfloat16, (unsigned short)h0[k]));
#pragma unroll
    for (int k = 0; k < 8; ++k)
      s += wp[8 + k] * __bfloat162float(__builtin_bit_cast(__hip_bfloat16, (unsigned short)h1[k]));
  } else {
    s = Vp127[(c << 10) + row];          // 32 partials, one per lane
  }
  s += __shfl_xor(s, 1);
  s += __shfl_xor(s, 2);
  s += __shfl_xor(s, 4);
  s += __shfl_xor(s, 8);
  s += __shfl_xor(s, 16);               // sum over 32 c-lanes
  if (c == 0)
    out[((row >> 3) << 10) + (t << 3) + (row & 7)] = s + bv[0];
}

extern "C" void kernel_launch(void* const* d_in, const int* in_sizes, int n_in,
                              void* d_out, int out_size, void* d_ws, size_t ws_size,
                              hipStream_t stream) {
  (void)in_sizes; (void)n_in; (void)out_size;
  const float* obs = (const float*)d_in[0];
  const float* W1  = (const float*)d_in[1];
  const float* b1  = (const float*)d_in[2];
  const float* Wih = (const float*)d_in[3];
  const float* bih = (const float*)d_in[4];
  const float* Whh = (const float*)d_in[5];
  const float* bhh = (const float*)d_in[6];
  const float* Wv  = (const float*)d_in[7];
  const float* bv  = (const float*)d_in[8];
  float* out = (float*)d_out;

  // ws (256 MiB): Hseq 127 slabs | X 128 slabs | spare 1 MiB (Vp127 + bar)
  //   obsB aliases Hseq slabs 0..31, W1B slab 32 (dead before h writes)
  char* ws = (char*)d_ws;
  bf16*  Hseq = (bf16*)ws;                                  // 127 MiB
  bf16*  obsB = Hseq;
  bf16*  W1B  = Hseq + (size_t)32 * SLAB_;
  bf16*  X    = (bf16*)(ws + (size_t)127 * SLAB_ * 2);      // 128 MiB
  char*  spare = ws + (size_t)255 * SLAB_ * 2;              // 1 MiB
  float* Vp127 = (float*)spare;                             // 128 KiB
  unsigned* bar = (unsigned*)(spare + 256 * 1024);          // 32 padded ctrs (4 KiB)
  const size_t need = (size_t)256 * SLAB_ * 2;
  if (ws_size < need) {
    fprintf(stderr, "[kernel_launch] WS TOO SMALL: need %zu have %zu\n",
            need, ws_size);
    fflush(stderr);
  }

  hipFuncSetAttribute((const void*)scan_kernel,
                      hipFuncAttributeMaxDynamicSharedMemorySize, 98304);

  cvt_obs_kernel<<<16384, 256, 0, stream>>>(obs, obsB);
  cvt_kernel<<<64, 256, 0, stream>>>(W1, W1B);
  bar_init_kernel<<<1, 256, 0, stream>>>(bar);
  xgemm_kernel<<<4096, 256, 0, stream>>>(obsB, W1B, b1, X);
  // 96 KB dyn-LDS (Wih 48K + Whh 48K, fully used) pins 1 block/CU
  scan_kernel<<<256, 256, 98304, stream>>>(Wih, Whh, bih, bhh, Wv, (const short*)X,
                                           Hseq, Vp127, bar);
  out_kernel<<<16384, 256, 0, stream>>>(Hseq, Vp127, Wv, bv, out);
}

// Round 5
// 1305.057 us; speedup vs baseline: 1.2952x; 1.0139x over previous
//
#include <hip/hip_runtime.h>
#include <hip/hip_bf16.h>
#include <cstdio>
#include <cstdint>

#define BS_   128
#define T_    128
#define A_    8
#define D_    128
#define H_    512
#define ROWS_ 1024           // BS*A
#define MTOT_ 131072         // BS*T*A
#define SLAB_ (ROWS_ * H_)   // one timestep slab (X or h), elements

typedef __hip_bfloat16 bf16;
typedef __attribute__((ext_vector_type(4))) float f32x4;
typedef __attribute__((ext_vector_type(8))) short s16x8;
typedef __attribute__((ext_vector_type(4))) short s16x4;

__device__ __forceinline__ void async_ld16(const void* g, const void* lds) {
  __builtin_amdgcn_global_load_lds((const __attribute__((address_space(1))) void*)g,
                                   (__attribute__((address_space(3))) void*)lds,
                                   16, 0, 0);
}
__device__ __forceinline__ s16x8 ldg8(const short* p) { return *(const s16x8*)p; }
__device__ __forceinline__ float sigm(float x) { return 1.f / (1.f + __expf(-x)); }
__device__ __forceinline__ float tanh_f(float x) {
  const float e = __expf(2.f * x);            // inf-safe
  return 1.f - 2.f / (e + 1.f);
}
__device__ __forceinline__ s16x8 cvt8(const float* p) {
  const float4 a = ((const float4*)p)[0];
  const float4 b = ((const float4*)p)[1];
  s16x8 r_;
  r_[0] = __builtin_bit_cast(short, __float2bfloat16(a.x));
  r_[1] = __builtin_bit_cast(short, __float2bfloat16(a.y));
  r_[2] = __builtin_bit_cast(short, __float2bfloat16(a.z));
  r_[3] = __builtin_bit_cast(short, __float2bfloat16(a.w));
  r_[4] = __builtin_bit_cast(short, __float2bfloat16(b.x));
  r_[5] = __builtin_bit_cast(short, __float2bfloat16(b.y));
  r_[6] = __builtin_bit_cast(short, __float2bfloat16(b.z));
  r_[7] = __builtin_bit_cast(short, __float2bfloat16(b.w));
  return r_;
}

// obs [b][t][a][d] fp32 -> obsB [t][b*8+a][d] bf16
__global__ __launch_bounds__(256)
void cvt_obs_kernel(const float* __restrict__ src, bf16* __restrict__ dst) {
  const int o = (blockIdx.x * 256 + threadIdx.x) << 2;
  const int d = o & 127, a = (o >> 7) & 7, t = (o >> 10) & 127, b = o >> 17;
  const float4 v = *(const float4*)(src + o);
  s16x4 pk;
  pk[0] = __builtin_bit_cast(short, __float2bfloat16(v.x));
  pk[1] = __builtin_bit_cast(short, __float2bfloat16(v.y));
  pk[2] = __builtin_bit_cast(short, __float2bfloat16(v.z));
  pk[3] = __builtin_bit_cast(short, __float2bfloat16(v.w));
  *(s16x4*)((short*)dst + ((((size_t)t << 10) + (b << 3) + a) << 7) + d) = pk;
}

__global__ __launch_bounds__(256)
void cvt_kernel(const float* __restrict__ src, bf16* __restrict__ dst) {
  const int i = (blockIdx.x * 256 + threadIdx.x) << 2;
  const float4 v = *(const float4*)(src + i);
  s16x4 o;
  o[0] = __builtin_bit_cast(short, __float2bfloat16(v.x));
  o[1] = __builtin_bit_cast(short, __float2bfloat16(v.y));
  o[2] = __builtin_bit_cast(short, __float2bfloat16(v.z));
  o[3] = __builtin_bit_cast(short, __float2bfloat16(v.w));
  *(s16x4*)((short*)dst + i) = o;
}

// 64 wave-slot counters (rt, w8), each padded to its own 128B line: 2048 dwords
__global__ __launch_bounds__(256)
void bar_init_kernel(unsigned* __restrict__ bar) {
  const int i = threadIdx.x;
#pragma unroll
  for (int k = 0; k < 8; ++k) bar[(k << 8) + i] = 0u;
}

// ---------------------------------------------------------------------------
// X = relu(obsB @ W1^T + b1)
// ---------------------------------------------------------------------------
__global__ __launch_bounds__(256)
void xgemm_kernel(const bf16* __restrict__ Ag, const bf16* __restrict__ Wg,
                  const float* __restrict__ bias, bf16* __restrict__ Og) {
  const int bid = blockIdx.x;
  const int m0 = (bid >> 2) << 7;
  const int n0 = (bid & 3) << 7;
  const int tid = threadIdx.x;
  const int w = tid >> 6, lane = tid & 63;
  const int r = lane & 15, q = lane >> 4;
  const int wm = w & 1, wn = w >> 1;

  __shared__ short As[128 * 32];
  __shared__ short Bs[128 * 32];

  f32x4 acc[4][4];
  const f32x4 vz = {0.f, 0.f, 0.f, 0.f};
#pragma unroll
  for (int i = 0; i < 4; ++i)
#pragma unroll
    for (int j = 0; j < 4; ++j) acc[i][j] = vz;

  const int lrow = lane >> 2;
  const int kcol = (lane & 3) << 3;

  for (int kt = 0; kt < 4; ++kt) {          // K = 128
    __syncthreads();
    const int kbase = kt << 5;
#pragma unroll
    for (int jj = 0; jj < 2; ++jj) {
      const int c = (w << 1) + jj;
      const int m = (c << 4) + lrow;
      async_ld16(Ag + (size_t)(m0 + m) * D_ + kbase + kcol, &As[c << 9]);
      async_ld16(Wg + (size_t)(n0 + m) * D_ + kbase + kcol, &Bs[c << 9]);
    }
    __syncthreads();

    s16x8 af[4], bfr[4];
#pragma unroll
    for (int x = 0; x < 4; ++x) {
      af[x]  = *(const s16x8*)&As[((wm << 6) + (x << 4) + r) * 32 + (q << 3)];
      bfr[x] = *(const s16x8*)&Bs[((wn << 6) + (x << 4) + r) * 32 + (q << 3)];
    }
#pragma unroll
    for (int i = 0; i < 4; ++i)
#pragma unroll
      for (int j = 0; j < 4; ++j)
        acc[i][j] = __builtin_amdgcn_mfma_f32_16x16x32_bf16(af[i], bfr[j],
                                                            acc[i][j], 0, 0, 0);
  }

#pragma unroll
  for (int j = 0; j < 4; ++j) {
    const int gn = n0 + (wn << 6) + (j << 4) + r;
    const float bb = bias[gn];
#pragma unroll
    for (int i = 0; i < 4; ++i) {
      const int gmb = m0 + (wm << 6) + (i << 4) + (q << 2);
#pragma unroll
      for (int ii = 0; ii < 4; ++ii) {
        const int gm = gmb + ii;
        Og[(size_t)gm * H_ + gn] =
            __float2bfloat16(fmaxf(acc[i][j][ii] + bb, 0.f));
      }
    }
  }
}

// ---------------------------------------------------------------------------
// Persistent GRU scan, round-13: 8 WAVES / 2 PER SIMD (TLP), round-2 protocol.
//  * Rounds 3-4 (XCD-local exchange) failed correctness/hung -> protocol
//    reverted to round-2's proven agent-scope scheme verbatim.
//  * Round-2 re-read: 1 wave/SIMD meant EVERY latency (poll RTT, h-load,
//    store drain, skew) was exposed on a single wave's timeline. Per-step
//    wave-serial busy ~6.8k cy vs 23.6k cy step -> ~17k un-hidable stall.
//    Load-depth changes were flat (r1->r2) because depth was never it.
//  * Fix: 512-thread blocks (8 waves, 2/SIMD), each wave owns ONE 16-row
//    MFMA tile (was two). Per-SIMD work unchanged; two independent waves
//    now interleave so one wave's stalls are filled by the other's
//    MFMA+gates. Sync = 64 slot counters (rt,w8), same per-wave
//    vmcnt(0) -> lane0 fetch_add arrive, same all-lane agent poll.
//  * LDS (96 KB: Wih+Whh lane-packed) still pins 1 block/CU.
// ---------------------------------------------------------------------------
__global__ __launch_bounds__(512, 1)
void scan_kernel(const float* __restrict__ Wih32, const float* __restrict__ Whh32,
                 const float* __restrict__ bih, const float* __restrict__ bhh,
                 const float* __restrict__ Wv, const short* __restrict__ Xs,
                 bf16* __restrict__ Hseq, float* __restrict__ Vp127,
                 unsigned* __restrict__ bar) {
  extern __shared__ short sm[];   // [0,24576): Wih  [24576,49152): Whh (lane-packed)

  const int bid = blockIdx.x;
  const int rt = bid & 7, jt = bid >> 3;
  const int j0 = jt << 4;
  const int tid = threadIdx.x;
  const int w = tid >> 6, lane = tid & 63;     // w in 0..7
  const int r = lane & 15, q = lane >> 4;
  const int rw = (rt << 7) + (w << 4);         // wave's 16 rows
  unsigned* __restrict__ barw = &bar[((rt << 3) + w) << 5];  // slot counter

  // ---- Wih + Whh slices fp32 -> bf16, lane-packed into LDS (once) ----
#pragma unroll
  for (int i = 0; i < 6; ++i) {
    const int c = (i << 3) + w;          // chunk 0..47 = (g, kt)
    const int g = c >> 4, kt = c & 15;
    const size_t woff = (size_t)((g << 9) + j0 + r) * H_ + (kt << 5) + (q << 3);
    *(s16x8*)&sm[(c << 9) + (lane << 3)]          = cvt8(Wih32 + woff);
    *(s16x8*)&sm[24576 + (c << 9) + (lane << 3)]  = cvt8(Whh32 + woff);
  }

  const int j = j0 + r;
  const float bR  = bih[j] + bhh[j];
  const float bZ  = bih[512 + j] + bhh[512 + j];
  const float bIN = bih[1024 + j];
  const float bHN = bhh[1024 + j];
  const float wvj = Wv[j];

  float hm[4] = {0.f, 0.f, 0.f, 0.f};
  const f32x4 vz = {0.f, 0.f, 0.f, 0.f};

  const size_t aoff0 = (size_t)(rw + r) * H_ + (q << 3);
  short* Hs = (short*)Hseq;

  __syncthreads();   // LDS staged (only barrier in the kernel)

  // ---- prologue: gi(0) from X slab 0, pinned full-depth issue ----
  f32x4 gia[3];
  {
    const short* xb = Xs;
    s16x8 ax[16];
#pragma unroll
    for (int p = 0; p < 16; ++p) ax[p] = ldg8(xb + aoff0 + (p << 5));
    __builtin_amdgcn_sched_barrier(0);
#pragma unroll
    for (int g = 0; g < 3; ++g) gia[g] = vz;
#pragma unroll
    for (int kt = 0; kt < 16; ++kt)
#pragma unroll
      for (int g = 0; g < 3; ++g) {
        const s16x8 b = *(const s16x8*)&sm[(((g << 4) + kt) << 9) + (lane << 3)];
        gia[g] = __builtin_amdgcn_mfma_f32_16x16x32_bf16(ax[kt], b, gia[g], 0, 0, 0);
      }
  }

  for (int t = 0; t < T_; ++t) {
    // ---- per-wave-slot wait (rows rw..rw+15 of slab t-1 complete) ----
    f32x4 gha[3];
#pragma unroll
    for (int g = 0; g < 3; ++g) gha[g] = vz;
    if (t > 0) {
      const unsigned tgt = (unsigned)t << 5;              // 32*t arrivals
      unsigned spins = 0;
      while (__hip_atomic_load(barw, __ATOMIC_RELAXED,
                               __HIP_MEMORY_SCOPE_AGENT) < tgt) {
        __builtin_amdgcn_s_sleep(1);
        if (++spins > 8000000u) break;                    // dead-man valve
      }

      // ---- gh: all 16 h-loads in flight (pinned) + LDS Whh B-frags ----
      const short* hb = Hs + (size_t)(t - 1) * SLAB_;
      s16x8 ah[16];
#pragma unroll
      for (int p = 0; p < 16; ++p) ah[p] = ldg8(hb + aoff0 + (p << 5));
      __builtin_amdgcn_sched_barrier(0); // keep loads issued & live
#pragma unroll
      for (int kt = 0; kt < 16; ++kt)
#pragma unroll
        for (int g = 0; g < 3; ++g) {
          const s16x8 b = *(const s16x8*)&sm[24576 + (((g << 4) + kt) << 9) + (lane << 3)];
          gha[g] = __builtin_amdgcn_mfma_f32_16x16x32_bf16(ah[kt], b, gha[g], 0, 0, 0);
        }
    }

    // ---- gates, h update; t=127: value partials from registers ----
    short* hrow = Hs + (size_t)t * SLAB_;
    const bool last = (t == T_ - 1);
#pragma unroll
    for (int ii = 0; ii < 4; ++ii) {
      const int row = rw + (q << 2) + ii;
      const float rr = sigm(gia[0][ii] + gha[0][ii] + bR);
      const float zz = sigm(gia[1][ii] + gha[1][ii] + bZ);
      const float nn = tanh_f(gia[2][ii] + bIN + rr * (gha[2][ii] + bHN));
      const float hnew = (1.f - zz) * nn + zz * hm[ii];
      hm[ii] = hnew;
      if (!last) {
        // packed lane-pair h store (cols j, j^1)
        const unsigned hv =
            (unsigned)(unsigned short)__builtin_bit_cast(unsigned short,
                                                         __float2bfloat16(hnew));
        const unsigned pv = (unsigned)__shfl_xor((int)hv, 1);
        if (!(r & 1)) {
          const unsigned pk = hv | (pv << 16);
          __hip_atomic_store((unsigned*)(hrow + (size_t)row * H_ + j0 + r), pk,
                             __ATOMIC_RELAXED, __HIP_MEMORY_SCOPE_AGENT);
        }
      } else {
        float vpv = wvj * hnew;
        vpv += __shfl_xor(vpv, 1);
        vpv += __shfl_xor(vpv, 2);
        vpv += __shfl_xor(vpv, 4);
        vpv += __shfl_xor(vpv, 8);       // sum 16 j-lanes
        if (r == 0) Vp127[(jt << 10) + row] = vpv;
      }
    }

    if (last) break;

    // ---- arrive: drain own h stores, bump slot counter ----
    asm volatile("s_waitcnt vmcnt(0)" ::: "memory");
    if (lane == 0)
      __hip_atomic_fetch_add(barw, 1u, __ATOMIC_RELAXED,
                             __HIP_MEMORY_SCOPE_AGENT);

    // ---- gi(t+1) in the arrive-shadow: full-depth X issue (pinned) ----
    {
      const short* xb = Xs + (size_t)(t + 1) * SLAB_;
      s16x8 ax[16];
#pragma unroll
      for (int p = 0; p < 16; ++p) ax[p] = ldg8(xb + aoff0 + (p << 5));
      __builtin_amdgcn_sched_barrier(0); // keep loads issued & live
#pragma unroll
      for (int g = 0; g < 3; ++g) gia[g] = vz;
#pragma unroll
      for (int kt = 0; kt < 16; ++kt)
#pragma unroll
        for (int g = 0; g < 3; ++g) {
          const s16x8 b = *(const s16x8*)&sm[(((g << 4) + kt) << 9) + (lane << 3)];
          gia[g] = __builtin_amdgcn_mfma_f32_16x16x32_bf16(ax[kt], b, gia[g], 0, 0, 0);
        }
    }
  }
}

// ---------------------------------------------------------------------------
// out[b][t][a] = bv + Wv . h_t(row)  (h from Hseq for t<127, Vp127 for t=127)
// block = (t, rowgroup of 8); thread (r8=tid>>5, c=tid&31): cols c*16..+15
// ---------------------------------------------------------------------------
__global__ __launch_bounds__(256)
void out_kernel(const bf16* __restrict__ Hseq, const float* __restrict__ Vp127,
                const float* __restrict__ Wv, const float* __restrict__ bv,
                float* __restrict__ out) {
  __shared__ float wvs[512];
  const int bid = blockIdx.x;           // 0..16383
  const int t = bid >> 7, rg = bid & 127;
  const int tid = threadIdx.x;
  const int r8 = tid >> 5, c = tid & 31;
  const int row = (rg << 3) + r8;
  if (tid < 128) *(float4*)&wvs[tid << 2] = *(const float4*)&Wv[tid << 2];
  __syncthreads();

  float s = 0.f;
  if (t < T_ - 1) {
    const short* hp = (const short*)Hseq + (size_t)t * SLAB_ + ((size_t)row << 9)
                    + (c << 4);
    const s16x8 h0 = ldg8(hp), h1 = ldg8(hp + 8);
    const float* wp = &wvs[c << 4];
#pragma unroll
    for (int k = 0; k < 8; ++k)
      s += wp[k] * __bfloat162float(__builtin_bit_cast(__hip_bfloat16, (unsigned short)h0[k]));
#pragma unroll
    for (int k = 0; k < 8; ++k)
      s += wp[8 + k] * __bfloat162float(__builtin_bit_cast(__hip_bfloat16, (unsigned short)h1[k]));
  } else {
    s = Vp127[(c << 10) + row];          // 32 partials, one per lane
  }
  s += __shfl_xor(s, 1);
  s += __shfl_xor(s, 2);
  s += __shfl_xor(s, 4);
  s += __shfl_xor(s, 8);
  s += __shfl_xor(s, 16);               // sum over 32 c-lanes
  if (c == 0)
    out[((row >> 3) << 10) + (t << 3) + (row & 7)] = s + bv[0];
}

extern "C" void kernel_launch(void* const* d_in, const int* in_sizes, int n_in,
                              void* d_out, int out_size, void* d_ws, size_t ws_size,
                              hipStream_t stream) {
  (void)in_sizes; (void)n_in; (void)out_size;
  const float* obs = (const float*)d_in[0];
  const float* W1  = (const float*)d_in[1];
  const float* b1  = (const float*)d_in[2];
  const float* Wih = (const float*)d_in[3];
  const float* bih = (const float*)d_in[4];
  const float* Whh = (const float*)d_in[5];
  const float* bhh = (const float*)d_in[6];
  const float* Wv  = (const float*)d_in[7];
  const float* bv  = (const float*)d_in[8];
  float* out = (float*)d_out;

  // ws (256 MiB): Hseq 127 slabs | X 128 slabs | spare 1 MiB (Vp127 + bar)
  //   obsB aliases Hseq slabs 0..31, W1B slab 32 (dead before h writes)
  char* ws = (char*)d_ws;
  bf16*  Hseq = (bf16*)ws;                                  // 127 MiB
  bf16*  obsB = Hseq;
  bf16*  W1B  = Hseq + (size_t)32 * SLAB_;
  bf16*  X    = (bf16*)(ws + (size_t)127 * SLAB_ * 2);      // 128 MiB
  char*  spare = ws + (size_t)255 * SLAB_ * 2;              // 1 MiB
  float* Vp127 = (float*)spare;                             // 128 KiB
  unsigned* bar = (unsigned*)(spare + 256 * 1024);          // 64 padded ctrs (8 KiB)
  const size_t need = (size_t)256 * SLAB_ * 2;
  if (ws_size < need) {
    fprintf(stderr, "[kernel_launch] WS TOO SMALL: need %zu have %zu\n",
            need, ws_size);
    fflush(stderr);
  }

  hipFuncSetAttribute((const void*)scan_kernel,
                      hipFuncAttributeMaxDynamicSharedMemorySize, 98304);

  cvt_obs_kernel<<<16384, 256, 0, stream>>>(obs, obsB);
  cvt_kernel<<<64, 256, 0, stream>>>(W1, W1B);
  bar_init_kernel<<<1, 256, 0, stream>>>(bar);
  xgemm_kernel<<<4096, 256, 0, stream>>>(obsB, W1B, b1, X);
  // 96 KB dyn-LDS (Wih 48K + Whh 48K) pins 1 block/CU; 8 waves = 2/SIMD
  scan_kernel<<<256, 512, 98304, stream>>>(Wih, Whh, bih, bhh, Wv, (const short*)X,
                                           Hseq, Vp127, bar);
  out_kernel<<<16384, 256, 0, stream>>>(Hseq, Vp127, Wv, bv, out);
}

// Round 6
// 1278.275 us; speedup vs baseline: 1.3224x; 1.0210x over previous
//
#include <hip/hip_runtime.h>
#include <hip/hip_bf16.h>
#include <cstdio>
#include <cstdint>

#define BS_   128
#define T_    128
#define A_    8
#define D_    128
#define H_    512
#define ROWS_ 1024           // BS*A
#define MTOT_ 131072         // BS*T*A
#define SLAB_ (ROWS_ * H_)   // one timestep slab (X or h), elements

typedef __hip_bfloat16 bf16;
typedef __attribute__((ext_vector_type(4))) float f32x4;
typedef __attribute__((ext_vector_type(8))) short s16x8;
typedef __attribute__((ext_vector_type(4))) short s16x4;

__device__ __forceinline__ void async_ld16(const void* g, const void* lds) {
  __builtin_amdgcn_global_load_lds((const __attribute__((address_space(1))) void*)g,
                                   (__attribute__((address_space(3))) void*)lds,
                                   16, 0, 0);
}
__device__ __forceinline__ s16x8 ldg8(const short* p) { return *(const s16x8*)p; }
__device__ __forceinline__ float sigm(float x) { return 1.f / (1.f + __expf(-x)); }
__device__ __forceinline__ float tanh_f(float x) {
  const float e = __expf(2.f * x);            // inf-safe
  return 1.f - 2.f / (e + 1.f);
}
__device__ __forceinline__ s16x8 cvt8(const float* p) {
  const float4 a = ((const float4*)p)[0];
  const float4 b = ((const float4*)p)[1];
  s16x8 r_;
  r_[0] = __builtin_bit_cast(short, __float2bfloat16(a.x));
  r_[1] = __builtin_bit_cast(short, __float2bfloat16(a.y));
  r_[2] = __builtin_bit_cast(short, __float2bfloat16(a.z));
  r_[3] = __builtin_bit_cast(short, __float2bfloat16(a.w));
  r_[4] = __builtin_bit_cast(short, __float2bfloat16(b.x));
  r_[5] = __builtin_bit_cast(short, __float2bfloat16(b.y));
  r_[6] = __builtin_bit_cast(short, __float2bfloat16(b.z));
  r_[7] = __builtin_bit_cast(short, __float2bfloat16(b.w));
  return r_;
}

// obs [b][t][a][d] fp32 -> obsB [t][b*8+a][d] bf16
__global__ __launch_bounds__(256)
void cvt_obs_kernel(const float* __restrict__ src, bf16* __restrict__ dst) {
  const int o = (blockIdx.x * 256 + threadIdx.x) << 2;
  const int d = o & 127, a = (o >> 7) & 7, t = (o >> 10) & 127, b = o >> 17;
  const float4 v = *(const float4*)(src + o);
  s16x4 pk;
  pk[0] = __builtin_bit_cast(short, __float2bfloat16(v.x));
  pk[1] = __builtin_bit_cast(short, __float2bfloat16(v.y));
  pk[2] = __builtin_bit_cast(short, __float2bfloat16(v.z));
  pk[3] = __builtin_bit_cast(short, __float2bfloat16(v.w));
  *(s16x4*)((short*)dst + ((((size_t)t << 10) + (b << 3) + a) << 7) + d) = pk;
}

__global__ __launch_bounds__(256)
void cvt_kernel(const float* __restrict__ src, bf16* __restrict__ dst) {
  const int i = (blockIdx.x * 256 + threadIdx.x) << 2;
  const float4 v = *(const float4*)(src + i);
  s16x4 o;
  o[0] = __builtin_bit_cast(short, __float2bfloat16(v.x));
  o[1] = __builtin_bit_cast(short, __float2bfloat16(v.y));
  o[2] = __builtin_bit_cast(short, __float2bfloat16(v.z));
  o[3] = __builtin_bit_cast(short, __float2bfloat16(v.w));
  *(s16x4*)((short*)dst + i) = o;
}

// 64 flag lines (rt, w8), each 128B = 32 jt-dwords: 2048 dwords = 8 KiB
__global__ __launch_bounds__(256)
void bar_init_kernel(unsigned* __restrict__ bar) {
  const int i = threadIdx.x;
#pragma unroll
  for (int k = 0; k < 8; ++k) bar[(k << 8) + i] = 0u;
}

// ---------------------------------------------------------------------------
// X = relu(obsB @ W1^T + b1)
// ---------------------------------------------------------------------------
__global__ __launch_bounds__(256)
void xgemm_kernel(const bf16* __restrict__ Ag, const bf16* __restrict__ Wg,
                  const float* __restrict__ bias, bf16* __restrict__ Og) {
  const int bid = blockIdx.x;
  const int m0 = (bid >> 2) << 7;
  const int n0 = (bid & 3) << 7;
  const int tid = threadIdx.x;
  const int w = tid >> 6, lane = tid & 63;
  const int r = lane & 15, q = lane >> 4;
  const int wm = w & 1, wn = w >> 1;

  __shared__ short As[128 * 32];
  __shared__ short Bs[128 * 32];

  f32x4 acc[4][4];
  const f32x4 vz = {0.f, 0.f, 0.f, 0.f};
#pragma unroll
  for (int i = 0; i < 4; ++i)
#pragma unroll
    for (int j = 0; j < 4; ++j) acc[i][j] = vz;

  const int lrow = lane >> 2;
  const int kcol = (lane & 3) << 3;

  for (int kt = 0; kt < 4; ++kt) {          // K = 128
    __syncthreads();
    const int kbase = kt << 5;
#pragma unroll
    for (int jj = 0; jj < 2; ++jj) {
      const int c = (w << 1) + jj;
      const int m = (c << 4) + lrow;
      async_ld16(Ag + (size_t)(m0 + m) * D_ + kbase + kcol, &As[c << 9]);
      async_ld16(Wg + (size_t)(n0 + m) * D_ + kbase + kcol, &Bs[c << 9]);
    }
    __syncthreads();

    s16x8 af[4], bfr[4];
#pragma unroll
    for (int x = 0; x < 4; ++x) {
      af[x]  = *(const s16x8*)&As[((wm << 6) + (x << 4) + r) * 32 + (q << 3)];
      bfr[x] = *(const s16x8*)&Bs[((wn << 6) + (x << 4) + r) * 32 + (q << 3)];
    }
#pragma unroll
    for (int i = 0; i < 4; ++i)
#pragma unroll
      for (int j = 0; j < 4; ++j)
        acc[i][j] = __builtin_amdgcn_mfma_f32_16x16x32_bf16(af[i], bfr[j],
                                                            acc[i][j], 0, 0, 0);
  }

#pragma unroll
  for (int j = 0; j < 4; ++j) {
    const int gn = n0 + (wn << 6) + (j << 4) + r;
    const float bb = bias[gn];
#pragma unroll
    for (int i = 0; i < 4; ++i) {
      const int gmb = m0 + (wm << 6) + (i << 4) + (q << 2);
#pragma unroll
      for (int ii = 0; ii < 4; ++ii) {
        const int gm = gmb + ii;
        Og[(size_t)gm * H_ + gn] =
            __float2bfloat16(fmaxf(acc[i][j][ii] + bb, 0.f));
      }
    }
  }
}

// ---------------------------------------------------------------------------
// Persistent GRU scan, round-14: STORE-BASED ARRIVAL FLAGS.
//  * Round-5 post-mortem: occupancy doubled (11.9->21.4) but time flat ->
//    the two waves/SIMD are PHASE-ALIGNED; TLP can't hide a latency all
//    waves hit simultaneously. Remaining suspect with the right magnitude:
//    each slot counter receives 32 agent-scope fetch_adds per step to ONE
//    cache line -- RMWs serialize at the coherence point (~100-200cy each
//    = 3-6k cy cascade) and the consumer detects only after the LAST one,
//    while 64 poll lanes bounce the same line.
//  * Fix: counter -> FLAG LINE. 32 distinct dwords per (rt,w) slot line;
//    producer jt does vmcnt(0) then ONE plain agent store flag[jt]=t+1
//    (no RMW serialization); consumer lanes 0..31 read the line in one
//    coalesced transaction and __all-check >= t.
//  * Ordering argument unchanged from proven round-2 protocol: h stores
//    drained by vmcnt(0) BEFORE the flag store issues; same agent scope,
//    same relaxed atomics -- only RMW->store changed.
//  * Everything else byte-identical to round-5 (512 thr, 8 waves, 16-row
//    wave tiles, Wih+Whh lane-packed LDS, pinned full-depth loads,
//    gi(t+1) in the arrive-shadow, t-indexed virgin h slabs).
// ---------------------------------------------------------------------------
__global__ __launch_bounds__(512, 1)
void scan_kernel(const float* __restrict__ Wih32, const float* __restrict__ Whh32,
                 const float* __restrict__ bih, const float* __restrict__ bhh,
                 const float* __restrict__ Wv, const short* __restrict__ Xs,
                 bf16* __restrict__ Hseq, float* __restrict__ Vp127,
                 unsigned* __restrict__ bar) {
  extern __shared__ short sm[];   // [0,24576): Wih  [24576,49152): Whh (lane-packed)

  const int bid = blockIdx.x;
  const int rt = bid & 7, jt = bid >> 3;
  const int j0 = jt << 4;
  const int tid = threadIdx.x;
  const int w = tid >> 6, lane = tid & 63;     // w in 0..7
  const int r = lane & 15, q = lane >> 4;
  const int rw = (rt << 7) + (w << 4);         // wave's 16 rows
  unsigned* __restrict__ flagw = &bar[((rt << 3) + w) << 5];  // 32 jt-dwords

  // ---- Wih + Whh slices fp32 -> bf16, lane-packed into LDS (once) ----
#pragma unroll
  for (int i = 0; i < 6; ++i) {
    const int c = (i << 3) + w;          // chunk 0..47 = (g, kt)
    const int g = c >> 4, kt = c & 15;
    const size_t woff = (size_t)((g << 9) + j0 + r) * H_ + (kt << 5) + (q << 3);
    *(s16x8*)&sm[(c << 9) + (lane << 3)]          = cvt8(Wih32 + woff);
    *(s16x8*)&sm[24576 + (c << 9) + (lane << 3)]  = cvt8(Whh32 + woff);
  }

  const int j = j0 + r;
  const float bR  = bih[j] + bhh[j];
  const float bZ  = bih[512 + j] + bhh[512 + j];
  const float bIN = bih[1024 + j];
  const float bHN = bhh[1024 + j];
  const float wvj = Wv[j];

  float hm[4] = {0.f, 0.f, 0.f, 0.f};
  const f32x4 vz = {0.f, 0.f, 0.f, 0.f};

  const size_t aoff0 = (size_t)(rw + r) * H_ + (q << 3);
  short* Hs = (short*)Hseq;

  __syncthreads();   // LDS staged (only barrier in the kernel)

  // ---- prologue: gi(0) from X slab 0, pinned full-depth issue ----
  f32x4 gia[3];
  {
    const short* xb = Xs;
    s16x8 ax[16];
#pragma unroll
    for (int p = 0; p < 16; ++p) ax[p] = ldg8(xb + aoff0 + (p << 5));
    __builtin_amdgcn_sched_barrier(0);
#pragma unroll
    for (int g = 0; g < 3; ++g) gia[g] = vz;
#pragma unroll
    for (int kt = 0; kt < 16; ++kt)
#pragma unroll
      for (int g = 0; g < 3; ++g) {
        const s16x8 b = *(const s16x8*)&sm[(((g << 4) + kt) << 9) + (lane << 3)];
        gia[g] = __builtin_amdgcn_mfma_f32_16x16x32_bf16(ax[kt], b, gia[g], 0, 0, 0);
      }
  }

  for (int t = 0; t < T_; ++t) {
    // ---- per-wave-slot wait: one coalesced flag-line read per check ----
    f32x4 gha[3];
#pragma unroll
    for (int g = 0; g < 3; ++g) gha[g] = vz;
    if (t > 0) {
      const unsigned tgt = (unsigned)t;
      unsigned spins = 0;
      for (;;) {
        const unsigned fl = __hip_atomic_load(&flagw[lane & 31],
                                              __ATOMIC_RELAXED,
                                              __HIP_MEMORY_SCOPE_AGENT);
        if (__all((int)(fl >= tgt))) break;
        __builtin_amdgcn_s_sleep(1);
        if (++spins > 8000000u) break;                    // dead-man valve
      }

      // ---- gh: all 16 h-loads in flight (pinned) + LDS Whh B-frags ----
      const short* hb = Hs + (size_t)(t - 1) * SLAB_;
      s16x8 ah[16];
#pragma unroll
      for (int p = 0; p < 16; ++p) ah[p] = ldg8(hb + aoff0 + (p << 5));
      __builtin_amdgcn_sched_barrier(0); // keep loads issued & live
#pragma unroll
      for (int kt = 0; kt < 16; ++kt)
#pragma unroll
        for (int g = 0; g < 3; ++g) {
          const s16x8 b = *(const s16x8*)&sm[24576 + (((g << 4) + kt) << 9) + (lane << 3)];
          gha[g] = __builtin_amdgcn_mfma_f32_16x16x32_bf16(ah[kt], b, gha[g], 0, 0, 0);
        }
    }

    // ---- gates, h update; t=127: value partials from registers ----
    short* hrow = Hs + (size_t)t * SLAB_;
    const bool last = (t == T_ - 1);
#pragma unroll
    for (int ii = 0; ii < 4; ++ii) {
      const int row = rw + (q << 2) + ii;
      const float rr = sigm(gia[0][ii] + gha[0][ii] + bR);
      const float zz = sigm(gia[1][ii] + gha[1][ii] + bZ);
      const float nn = tanh_f(gia[2][ii] + bIN + rr * (gha[2][ii] + bHN));
      const float hnew = (1.f - zz) * nn + zz * hm[ii];
      hm[ii] = hnew;
      if (!last) {
        // packed lane-pair h store (cols j, j^1)
        const unsigned hv =
            (unsigned)(unsigned short)__builtin_bit_cast(unsigned short,
                                                         __float2bfloat16(hnew));
        const unsigned pv = (unsigned)__shfl_xor((int)hv, 1);
        if (!(r & 1)) {
          const unsigned pk = hv | (pv << 16);
          __hip_atomic_store((unsigned*)(hrow + (size_t)row * H_ + j0 + r), pk,
                             __ATOMIC_RELAXED, __HIP_MEMORY_SCOPE_AGENT);
        }
      } else {
        float vpv = wvj * hnew;
        vpv += __shfl_xor(vpv, 1);
        vpv += __shfl_xor(vpv, 2);
        vpv += __shfl_xor(vpv, 4);
        vpv += __shfl_xor(vpv, 8);       // sum 16 j-lanes
        if (r == 0) Vp127[(jt << 10) + row] = vpv;
      }
    }

    if (last) break;

    // ---- arrive: drain own h stores, then ONE flag store (no RMW) ----
    asm volatile("s_waitcnt vmcnt(0)" ::: "memory");
    if (lane == 0)
      __hip_atomic_store(&flagw[jt], (unsigned)(t + 1), __ATOMIC_RELAXED,
                         __HIP_MEMORY_SCOPE_AGENT);

    // ---- gi(t+1) in the arrive-shadow: full-depth X issue (pinned) ----
    {
      const short* xb = Xs + (size_t)(t + 1) * SLAB_;
      s16x8 ax[16];
#pragma unroll
      for (int p = 0; p < 16; ++p) ax[p] = ldg8(xb + aoff0 + (p << 5));
      __builtin_amdgcn_sched_barrier(0); // keep loads issued & live
#pragma unroll
      for (int g = 0; g < 3; ++g) gia[g] = vz;
#pragma unroll
      for (int kt = 0; kt < 16; ++kt)
#pragma unroll
        for (int g = 0; g < 3; ++g) {
          const s16x8 b = *(const s16x8*)&sm[(((g << 4) + kt) << 9) + (lane << 3)];
          gia[g] = __builtin_amdgcn_mfma_f32_16x16x32_bf16(ax[kt], b, gia[g], 0, 0, 0);
        }
    }
  }
}

// ---------------------------------------------------------------------------
// out[b][t][a] = bv + Wv . h_t(row)  (h from Hseq for t<127, Vp127 for t=127)
// block = (t, rowgroup of 8); thread (r8=tid>>5, c=tid&31): cols c*16..+15
// ---------------------------------------------------------------------------
__global__ __launch_bounds__(256)
void out_kernel(const bf16* __restrict__ Hseq, const float* __restrict__ Vp127,
                const float* __restrict__ Wv, const float* __restrict__ bv,
                float* __restrict__ out) {
  __shared__ float wvs[512];
  const int bid = blockIdx.x;           // 0..16383
  const int t = bid >> 7, rg = bid & 127;
  const int tid = threadIdx.x;
  const int r8 = tid >> 5, c = tid & 31;
  const int row = (rg << 3) + r8;
  if (tid < 128) *(float4*)&wvs[tid << 2] = *(const float4*)&Wv[tid << 2];
  __syncthreads();

  float s = 0.f;
  if (t < T_ - 1) {
    const short* hp = (const short*)Hseq + (size_t)t * SLAB_ + ((size_t)row << 9)
                    + (c << 4);
    const s16x8 h0 = ldg8(hp), h1 = ldg8(hp + 8);
    const float* wp = &wvs[c << 4];
#pragma unroll
    for (int k = 0; k < 8; ++k)
      s += wp[k] * __bfloat162float(__builtin_bit_cast(__hip_bfloat16, (unsigned short)h0[k]));
#pragma unroll
    for (int k = 0; k < 8; ++k)
      s += wp[8 + k] * __bfloat162float(__builtin_bit_cast(__hip_bfloat16, (unsigned short)h1[k]));
  } else {
    s = Vp127[(c << 10) + row];          // 32 partials, one per lane
  }
  s += __shfl_xor(s, 1);
  s += __shfl_xor(s, 2);
  s += __shfl_xor(s, 4);
  s += __shfl_xor(s, 8);
  s += __shfl_xor(s, 16);               // sum over 32 c-lanes
  if (c == 0)
    out[((row >> 3) << 10) + (t << 3) + (row & 7)] = s + bv[0];
}

extern "C" void kernel_launch(void* const* d_in, const int* in_sizes, int n_in,
                              void* d_out, int out_size, void* d_ws, size_t ws_size,
                              hipStream_t stream) {
  (void)in_sizes; (void)n_in; (void)out_size;
  const float* obs = (const float*)d_in[0];
  const float* W1  = (const float*)d_in[1];
  const float* b1  = (const float*)d_in[2];
  const float* Wih = (const float*)d_in[3];
  const float* bih = (const float*)d_in[4];
  const float* Whh = (const float*)d_in[5];
  const float* bhh = (const float*)d_in[6];
  const float* Wv  = (const float*)d_in[7];
  const float* bv  = (const float*)d_in[8];
  float* out = (float*)d_out;

  // ws (256 MiB): Hseq 127 slabs | X 128 slabs | spare 1 MiB (Vp127 + bar)
  //   obsB aliases Hseq slabs 0..31, W1B slab 32 (dead before h writes)
  char* ws = (char*)d_ws;
  bf16*  Hseq = (bf16*)ws;                                  // 127 MiB
  bf16*  obsB = Hseq;
  bf16*  W1B  = Hseq + (size_t)32 * SLAB_;
  bf16*  X    = (bf16*)(ws + (size_t)127 * SLAB_ * 2);      // 128 MiB
  char*  spare = ws + (size_t)255 * SLAB_ * 2;              // 1 MiB
  float* Vp127 = (float*)spare;                             // 128 KiB
  unsigned* bar = (unsigned*)(spare + 256 * 1024);          // 64 flag lines (8 KiB)
  const size_t need = (size_t)256 * SLAB_ * 2;
  if (ws_size < need) {
    fprintf(stderr, "[kernel_launch] WS TOO SMALL: need %zu have %zu\n",
            need, ws_size);
    fflush(stderr);
  }

  hipFuncSetAttribute((const void*)scan_kernel,
                      hipFuncAttributeMaxDynamicSharedMemorySize, 98304);

  cvt_obs_kernel<<<16384, 256, 0, stream>>>(obs, obsB);
  cvt_kernel<<<64, 256, 0, stream>>>(W1, W1B);
  bar_init_kernel<<<1, 256, 0, stream>>>(bar);
  xgemm_kernel<<<4096, 256, 0, stream>>>(obsB, W1B, b1, X);
  // 96 KB dyn-LDS (Wih 48K + Whh 48K) pins 1 block/CU; 8 waves = 2/SIMD
  scan_kernel<<<256, 512, 98304, stream>>>(Wih, Whh, bih, bhh, Wv, (const short*)X,
                                           Hseq, Vp127, bar);
  out_kernel<<<16384, 256, 0, stream>>>(Hseq, Vp127, Wv, bv, out);
}